// Round 6
// baseline (3008.932 us; speedup 1.0000x reference)
//
#include <hip/hip_runtime.h>

typedef _Float16 half_t;
typedef _Float16 h2_t __attribute__((ext_vector_type(2)));
typedef _Float16 h4_t __attribute__((ext_vector_type(4)));
typedef _Float16 h8_t __attribute__((ext_vector_type(8)));
typedef float f32x4 __attribute__((ext_vector_type(4)));
typedef unsigned int uint32;

#define BQ 64
#define TT 2048
#define EE 256
#define HH 256

#if defined(__has_builtin)
#if __has_builtin(__builtin_amdgcn_fdot2)
#define HAVE_FDOT2 1
#endif
#if __has_builtin(__builtin_amdgcn_update_dpp)
#define HAVE_DPP 1
#endif
#if __has_builtin(__builtin_amdgcn_rcpf)
#define FRCP(x) __builtin_amdgcn_rcpf(x)
#endif
#endif
#ifndef FRCP
#define FRCP(x) (1.0f / (x))
#endif

__device__ __forceinline__ float fdot2_acc(h2_t a, h2_t b, float c) {
#ifdef HAVE_FDOT2
  return __builtin_amdgcn_fdot2(a, b, c, false);
#else
  return c + (float)a[0] * (float)b[0] + (float)a[1] * (float)b[1];
#endif
}

__device__ __forceinline__ float dot8(h8_t w, h8_t h, float acc) {
  acc = fdot2_acc(__builtin_shufflevector(w, w, 0, 1), __builtin_shufflevector(h, h, 0, 1), acc);
  acc = fdot2_acc(__builtin_shufflevector(w, w, 2, 3), __builtin_shufflevector(h, h, 2, 3), acc);
  acc = fdot2_acc(__builtin_shufflevector(w, w, 4, 5), __builtin_shufflevector(h, h, 4, 5), acc);
  acc = fdot2_acc(__builtin_shufflevector(w, w, 6, 7), __builtin_shufflevector(h, h, 6, 7), acc);
  return acc;
}

// cross-lane move via DPP quad_perm (VALU pipe). 0xB1 = xor1, 0x4E = xor2.
template <int CTRL>
__device__ __forceinline__ float dpp_mov(float v) {
#ifdef HAVE_DPP
  return __builtin_bit_cast(
      float, __builtin_amdgcn_update_dpp(0, __builtin_bit_cast(int, v), CTRL, 0xF, 0xF, true));
#else
  return __shfl_xor(v, (CTRL == 0xB1) ? 1 : 2, 64);
#endif
}

// full sum over the 4 lanes of a quad, result in every lane (pure VALU)
__device__ __forceinline__ float reduce4(float v) {
  v += dpp_mov<0xB1>(v);
  v += dpp_mov<0x4E>(v);
  return v;
}

// barrier that drains LDS only: global prefetch stays in flight
__device__ __forceinline__ void barrier_lgkm() {
  asm volatile("s_waitcnt lgkmcnt(0)\n\ts_barrier" ::: "memory");
}

__device__ __forceinline__ float sigmoid_f(float x) {
  x = fminf(fmaxf(x, -30.f), 30.f);
  return FRCP(1.f + __expf(-x));
}

// ---------------- Phase A: input projections ----------------
// One block per timestep t: A (x rows, all 64 batches) staged ONCE, then 16
// N-chunks of 48 gate-rows with double-buffered, padded B tiles (x read 1x).
__device__ __forceinline__ const float4* wsrc(int n, int col, const float* Wu,
                                              const float* Wr, const float* Wn) {
  const int gsel = n >> 8, jj = n & 255;
  const float* W = (gsel == 0) ? Wu : (gsel == 1) ? Wr : Wn;
  return (const float4*)(W + (size_t)jj * (EE + HH) + col);
}

__global__ __launch_bounds__(256) void gru_xproj(
    const float* __restrict__ x,
    const float* __restrict__ Wu, const float* __restrict__ bu,
    const float* __restrict__ Wr, const float* __restrict__ br,
    const float* __restrict__ Wn, const float* __restrict__ bn,
    float* __restrict__ hs, half_t* __restrict__ nbuf, int t0)
{
  __shared__ half_t Asm[64][264];     // +8 pad: 2-way banks only
  __shared__ half_t Bsm[2][48][264];
  const int tid = threadIdx.x;
  const int tl = blockIdx.x;
  const int t = t0 + tl;

  // stage A: flat float4 index q = tid + 256k; row=q>>6 (batch), col=(q&63)*4
#pragma unroll
  for (int k = 0; k < 16; ++k) {
    int q = tid + 256 * k;
    int row = q >> 6, col = (q & 63) * 4;
    float4 v = *(const float4*)(x + ((size_t)row * TT + t) * EE + col);
    h4_t h; h[0] = (half_t)v.x; h[1] = (half_t)v.y; h[2] = (half_t)v.z; h[3] = (half_t)v.w;
    *(h4_t*)(&Asm[row][col]) = h;
  }
  // stage B chunk 0
#pragma unroll
  for (int k = 0; k < 12; ++k) {
    int q = tid + 256 * k;
    int row = q >> 6, col = (q & 63) * 4;
    float4 v = *wsrc(row, col, Wu, Wr, Wn);
    h4_t h; h[0] = (half_t)v.x; h[1] = (half_t)v.y; h[2] = (half_t)v.z; h[3] = (half_t)v.w;
    *(h4_t*)(&Bsm[0][row][col]) = h;
  }
  __syncthreads();

  const int wv = tid >> 6, lane = tid & 63;
  const int rowa = wv * 16 + (lane & 15);
  const int koff = (lane >> 4) * 8;
  h8_t af[8];
#pragma unroll
  for (int ki = 0; ki < 8; ++ki) af[ki] = *(const h8_t*)&Asm[rowa][ki * 32 + koff];

  const int colc = lane & 15;
  const int rbase = wv * 16 + (lane >> 4) * 4;

  for (int c = 0; c < 16; ++c) {
    const int cur = c & 1;
    // prefetch next B chunk into regs
    float4 pf[12];
    if (c < 15) {
#pragma unroll
      for (int k = 0; k < 12; ++k) {
        int q = tid + 256 * k;
        int row = q >> 6, col = (q & 63) * 4;
        pf[k] = *wsrc((c + 1) * 48 + row, col, Wu, Wr, Wn);
      }
    }
    // MFMA on current chunk
    f32x4 acc0 = {0.f, 0.f, 0.f, 0.f}, acc1 = acc0, acc2 = acc0;
#pragma unroll
    for (int ki = 0; ki < 8; ++ki) {
      h8_t b0 = *(const h8_t*)&Bsm[cur][0  + (lane & 15)][ki * 32 + koff];
      h8_t b1 = *(const h8_t*)&Bsm[cur][16 + (lane & 15)][ki * 32 + koff];
      h8_t b2 = *(const h8_t*)&Bsm[cur][32 + (lane & 15)][ki * 32 + koff];
      acc0 = __builtin_amdgcn_mfma_f32_16x16x32_f16(af[ki], b0, acc0, 0, 0, 0);
      acc1 = __builtin_amdgcn_mfma_f32_16x16x32_f16(af[ki], b1, acc1, 0, 0, 0);
      acc2 = __builtin_amdgcn_mfma_f32_16x16x32_f16(af[ki], b2, acc2, 0, 0, 0);
    }
    // write prefetched chunk to the other buffer
    if (c < 15) {
#pragma unroll
      for (int k = 0; k < 12; ++k) {
        int q = tid + 256 * k;
        int row = q >> 6, col = (q & 63) * 4;
        float4 v = pf[k];
        h4_t h; h[0] = (half_t)v.x; h[1] = (half_t)v.y; h[2] = (half_t)v.z; h[3] = (half_t)v.w;
        *(h4_t*)(&Bsm[cur ^ 1][row][col]) = h;
      }
    }
    // epilogue for chunk c (D: col = lane&15, row = (lane>>4)*4 + reg)
#pragma unroll
    for (int nt = 0; nt < 3; ++nt) {
      f32x4 a = (nt == 0) ? acc0 : (nt == 1) ? acc1 : acc2;
      int n = c * 48 + nt * 16 + colc;
      int gsel = n >> 8, jj = n & 255;
      const float* bp = (gsel == 0) ? bu : (gsel == 1) ? br : bn;
      float bias = bp[jj];
#pragma unroll
      for (int rr = 0; rr < 4; ++rr) {
        int m = rbase + rr;  // batch
        half_t hv = (half_t)(a[rr] + bias);
        if (gsel < 2) {
          ((unsigned short*)hs)[(((size_t)m * TT + t) * HH + jj) * 2 + gsel] =
              __builtin_bit_cast(unsigned short, hv);
        } else {
          nbuf[((size_t)tl * BQ + m) * HH + jj] = hv;
        }
      }
    }
    __syncthreads();
  }
}

// ---------------- Phase B: sequential scan ----------------
// 1024 threads (16 waves, 4/SIMD -- launch_bounds(1024) forces <=128 VGPR and
// the design FITS: 96 weight VGPRs + ~25 temps). Quad g = tid>>2 owns row g of
// u, r, n; lane i = tid&3 holds K-slice {8*(i+4c) : c<8}. Row-reduce = pure
// quad_perm DPP (xor1+xor2); all 4 lanes redundantly compute the scalar tail,
// h master stays in registers. Barriers drain lgkm only (global gate prefetch,
// depth 2, survives). rt uses Wu/xu, zt uses Wr/xr (reference naming quirk);
// n-gate input is (rt*h) @ Wn_h^T.
__global__ __launch_bounds__(1024) void gru_rec(
    float* __restrict__ hs,           // u/r gate stash + h output
    const half_t* __restrict__ nbuf,  // n-gate chunk
    const float* __restrict__ h0,
    const float* __restrict__ Wu, const float* __restrict__ Wr,
    const float* __restrict__ Wn,
    float* __restrict__ ht, float* __restrict__ hws,
    int t0, int t1)
{
  __shared__ __align__(16) half_t h2buf[256];
  __shared__ __align__(16) half_t rh2buf[256];

  const int b = blockIdx.x;
  const int tid = threadIdx.x;
  const int g = tid >> 2;  // gate row 0..255 (same row for u, r, n)
  const int i = tid & 3;   // K-quarter

  // weights: w*8[c] = W[g][EE + 8*(i+4c) .. +8], c = 0..7 (64 halves per gate)
  h8_t wu8[8], wr8[8], wn8[8];
  {
    const float* pu = Wu + (size_t)g * (EE + HH) + EE;
    const float* pr = Wr + (size_t)g * (EE + HH) + EE;
    const float* pn = Wn + (size_t)g * (EE + HH) + EE;
#pragma unroll
    for (int c = 0; c < 8; ++c) {
      int k0 = 8 * (i + 4 * c);
      float4 a0 = *(const float4*)(pu + k0);
      float4 a1 = *(const float4*)(pu + k0 + 4);
      h8_t w;
      w[0] = (half_t)a0.x; w[1] = (half_t)a0.y; w[2] = (half_t)a0.z; w[3] = (half_t)a0.w;
      w[4] = (half_t)a1.x; w[5] = (half_t)a1.y; w[6] = (half_t)a1.z; w[7] = (half_t)a1.w;
      wu8[c] = w;
      a0 = *(const float4*)(pr + k0);
      a1 = *(const float4*)(pr + k0 + 4);
      w[0] = (half_t)a0.x; w[1] = (half_t)a0.y; w[2] = (half_t)a0.z; w[3] = (half_t)a0.w;
      w[4] = (half_t)a1.x; w[5] = (half_t)a1.y; w[6] = (half_t)a1.z; w[7] = (half_t)a1.w;
      wr8[c] = w;
      a0 = *(const float4*)(pn + k0);
      a1 = *(const float4*)(pn + k0 + 4);
      w[0] = (half_t)a0.x; w[1] = (half_t)a0.y; w[2] = (half_t)a0.z; w[3] = (half_t)a0.w;
      w[4] = (half_t)a1.x; w[5] = (half_t)a1.y; w[6] = (half_t)a1.z; w[7] = (half_t)a1.w;
      wn8[c] = w;
    }
  }

  float hm;
  {
    const float* hsrc = (t0 == 0) ? (h0 + (size_t)b * HH) : (hws + (size_t)b * HH);
    hm = hsrc[g];
    if (tid < 256) h2buf[tid] = (half_t)hsrc[tid];
  }
  __syncthreads();

  const uint32* urp = (const uint32*)hs + ((size_t)b * TT + t0) * HH + g;
  const half_t* np = nbuf + (size_t)b * HH + g;
  float* hout = hs + ((size_t)b * TT + t0) * HH + g;

  const int nT = t1 - t0;
  uint32 ur0 = urp[0];
  half_t xn0 = np[0];
  const int i1 = (nT > 1) ? 1 : 0;
  uint32 ur1 = urp[(size_t)i1 * HH];
  half_t xn1 = np[(size_t)i1 * BQ * HH];

  const h8_t* hq = (const h8_t*)h2buf;
  const h8_t* rq = (const h8_t*)rh2buf;

  for (int tl = 0; tl < nT; ++tl) {
    const int t2 = (tl + 2 < nT) ? (tl + 2) : (nT - 1);
    uint32 ur2 = urp[(size_t)t2 * HH];           // stays in flight across barriers
    half_t xn2 = np[(size_t)t2 * BQ * HH];

    // ---- phase 1: u,r matvecs over h ----
    float au = 0.f, ar = 0.f;
#pragma unroll
    for (int c = 0; c < 8; ++c) {
      h8_t hv = hq[i + 4 * c];
      au = dot8(wu8[c], hv, au);
      ar = dot8(wr8[c], hv, ar);
    }
    float suf = reduce4(au);
    float srf = reduce4(ar);
    float xu = (float)__builtin_bit_cast(half_t, (unsigned short)(ur0 & 0xffffu));
    float xr = (float)__builtin_bit_cast(half_t, (unsigned short)(ur0 >> 16));
    float rt = sigmoid_f(xu + suf);
    float zt = sigmoid_f(xr + srf);
    if (i == 0) rh2buf[g] = (half_t)(rt * hm);  // rt * h (pre-matmul!)
    barrier_lgkm();

    // ---- phase 2: n matvec over rt*h, state update ----
    float an = 0.f;
#pragma unroll
    for (int c = 0; c < 8; ++c) {
      an = dot8(wn8[c], rq[i + 4 * c], an);
    }
    float snf = reduce4(an);
    float pre = (float)xn0 + snf;
    pre = fminf(fmaxf(pre, -15.f), 15.f);
    float e = __expf(-2.f * pre);
    float ntv = (1.f - e) * FRCP(1.f + e);  // tanh
    float hn = (1.f - zt) * ntv + zt * hm;
    hm = hn;
    if (i == 0) {
      h2buf[g] = (half_t)hn;
      hout[(size_t)tl * HH] = hn;  // overwrites the consumed u/r gate slot
    }
    barrier_lgkm();

    ur0 = ur1; ur1 = ur2;
    xn0 = xn1; xn1 = xn2;
  }

  if (i == 0) {
    if (t1 == TT) ht[(size_t)b * HH + g] = hm;
    else hws[(size_t)b * HH + g] = hm;
  }
}

extern "C" void kernel_launch(void* const* d_in, const int* in_sizes, int n_in,
                              void* d_out, int out_size, void* d_ws, size_t ws_size,
                              hipStream_t stream)
{
  (void)in_sizes; (void)n_in; (void)out_size;
  const float* x  = (const float*)d_in[0];
  const float* h0 = (const float*)d_in[1];
  const float* Wu = (const float*)d_in[2];
  const float* bu = (const float*)d_in[3];
  const float* Wr = (const float*)d_in[4];
  const float* br = (const float*)d_in[5];
  const float* Wn = (const float*)d_in[6];
  const float* bn = (const float*)d_in[7];
  float* hs = (float*)d_out;
  float* ht = hs + (size_t)BQ * TT * HH;
  float* hws = (float*)d_ws;                      // 64 KB h carry
  half_t* nbuf = (half_t*)((char*)d_ws + 65536);  // n-gate chunks

  const size_t per_step = (size_t)BQ * HH * sizeof(half_t);  // 32 KB/step
  size_t avail = (ws_size > 65536) ? ws_size - 65536 : 0;
  int Tc = (int)(avail / per_step);
  if (Tc > TT) Tc = TT;
  if (Tc < 1) Tc = 1;

  for (int t0 = 0; t0 < TT; t0 += Tc) {
    int tc = (TT - t0 < Tc) ? (TT - t0) : Tc;
    gru_xproj<<<dim3(tc), 256, 0, stream>>>(x, Wu, bu, Wr, br, Wn, bn, hs, nbuf, t0);
    gru_rec<<<dim3(BQ), 1024, 0, stream>>>(hs, nbuf, h0, Wu, Wr, Wn, ht, hws, t0, t0 + tc);
  }
}

// Round 7
// 2671.638 us; speedup vs baseline: 1.1262x; 1.1262x over previous
//
#include <hip/hip_runtime.h>

typedef _Float16 half_t;
typedef _Float16 h2_t __attribute__((ext_vector_type(2)));
typedef _Float16 h4_t __attribute__((ext_vector_type(4)));
typedef _Float16 h8_t __attribute__((ext_vector_type(8)));
typedef float f32x4 __attribute__((ext_vector_type(4)));
typedef unsigned int uint32;

#define BQ 64
#define TT 2048
#define EE 256
#define HH 256

#if defined(__has_builtin)
#if __has_builtin(__builtin_amdgcn_rcpf)
#define FRCP(x) __builtin_amdgcn_rcpf(x)
#endif
#endif
#ifndef FRCP
#define FRCP(x) (1.0f / (x))
#endif

// barrier that drains LDS only: global prefetch stays in flight
__device__ __forceinline__ void barrier_lgkm() {
  asm volatile("s_waitcnt lgkmcnt(0)\n\ts_barrier" ::: "memory");
}

__device__ __forceinline__ float sigmoid_f(float x) {
  x = fminf(fmaxf(x, -30.f), 30.f);
  return FRCP(1.f + __expf(-x));
}

__device__ __forceinline__ h8_t cvt_w8(const float* p) {
  float4 a0 = *(const float4*)p;
  float4 a1 = *(const float4*)(p + 4);
  h8_t w;
  w[0] = (half_t)a0.x; w[1] = (half_t)a0.y; w[2] = (half_t)a0.z; w[3] = (half_t)a0.w;
  w[4] = (half_t)a1.x; w[5] = (half_t)a1.y; w[6] = (half_t)a1.z; w[7] = (half_t)a1.w;
  return w;
}

// ---------------- Phase A: input projections ----------------
// One block per timestep t: A (x rows, all 64 batches) staged ONCE, then 16
// N-chunks of 48 gate-rows with double-buffered, padded B tiles (x read 1x).
__device__ __forceinline__ const float4* wsrc(int n, int col, const float* Wu,
                                              const float* Wr, const float* Wn) {
  const int gsel = n >> 8, jj = n & 255;
  const float* W = (gsel == 0) ? Wu : (gsel == 1) ? Wr : Wn;
  return (const float4*)(W + (size_t)jj * (EE + HH) + col);
}

__global__ __launch_bounds__(256) void gru_xproj(
    const float* __restrict__ x,
    const float* __restrict__ Wu, const float* __restrict__ bu,
    const float* __restrict__ Wr, const float* __restrict__ br,
    const float* __restrict__ Wn, const float* __restrict__ bn,
    float* __restrict__ hs, half_t* __restrict__ nbuf, int t0)
{
  __shared__ half_t Asm[64][264];     // +8 pad: 2-way banks only
  __shared__ half_t Bsm[2][48][264];
  const int tid = threadIdx.x;
  const int tl = blockIdx.x;
  const int t = t0 + tl;

  // stage A: flat float4 index q = tid + 256k; row=q>>6 (batch), col=(q&63)*4
#pragma unroll
  for (int k = 0; k < 16; ++k) {
    int q = tid + 256 * k;
    int row = q >> 6, col = (q & 63) * 4;
    float4 v = *(const float4*)(x + ((size_t)row * TT + t) * EE + col);
    h4_t h; h[0] = (half_t)v.x; h[1] = (half_t)v.y; h[2] = (half_t)v.z; h[3] = (half_t)v.w;
    *(h4_t*)(&Asm[row][col]) = h;
  }
  // stage B chunk 0
#pragma unroll
  for (int k = 0; k < 12; ++k) {
    int q = tid + 256 * k;
    int row = q >> 6, col = (q & 63) * 4;
    float4 v = *wsrc(row, col, Wu, Wr, Wn);
    h4_t h; h[0] = (half_t)v.x; h[1] = (half_t)v.y; h[2] = (half_t)v.z; h[3] = (half_t)v.w;
    *(h4_t*)(&Bsm[0][row][col]) = h;
  }
  __syncthreads();

  const int wv = tid >> 6, lane = tid & 63;
  const int rowa = wv * 16 + (lane & 15);
  const int koff = (lane >> 4) * 8;
  h8_t af[8];
#pragma unroll
  for (int ki = 0; ki < 8; ++ki) af[ki] = *(const h8_t*)&Asm[rowa][ki * 32 + koff];

  const int colc = lane & 15;
  const int rbase = wv * 16 + (lane >> 4) * 4;

  for (int c = 0; c < 16; ++c) {
    const int cur = c & 1;
    // prefetch next B chunk into regs
    float4 pf[12];
    if (c < 15) {
#pragma unroll
      for (int k = 0; k < 12; ++k) {
        int q = tid + 256 * k;
        int row = q >> 6, col = (q & 63) * 4;
        pf[k] = *wsrc((c + 1) * 48 + row, col, Wu, Wr, Wn);
      }
    }
    // MFMA on current chunk
    f32x4 acc0 = {0.f, 0.f, 0.f, 0.f}, acc1 = acc0, acc2 = acc0;
#pragma unroll
    for (int ki = 0; ki < 8; ++ki) {
      h8_t b0 = *(const h8_t*)&Bsm[cur][0  + (lane & 15)][ki * 32 + koff];
      h8_t b1 = *(const h8_t*)&Bsm[cur][16 + (lane & 15)][ki * 32 + koff];
      h8_t b2 = *(const h8_t*)&Bsm[cur][32 + (lane & 15)][ki * 32 + koff];
      acc0 = __builtin_amdgcn_mfma_f32_16x16x32_f16(af[ki], b0, acc0, 0, 0, 0);
      acc1 = __builtin_amdgcn_mfma_f32_16x16x32_f16(af[ki], b1, acc1, 0, 0, 0);
      acc2 = __builtin_amdgcn_mfma_f32_16x16x32_f16(af[ki], b2, acc2, 0, 0, 0);
    }
    // write prefetched chunk to the other buffer
    if (c < 15) {
#pragma unroll
      for (int k = 0; k < 12; ++k) {
        int q = tid + 256 * k;
        int row = q >> 6, col = (q & 63) * 4;
        float4 v = pf[k];
        h4_t h; h[0] = (half_t)v.x; h[1] = (half_t)v.y; h[2] = (half_t)v.z; h[3] = (half_t)v.w;
        *(h4_t*)(&Bsm[cur ^ 1][row][col]) = h;
      }
    }
    // epilogue for chunk c (D: col = lane&15, row = (lane>>4)*4 + reg)
#pragma unroll
    for (int nt = 0; nt < 3; ++nt) {
      f32x4 a = (nt == 0) ? acc0 : (nt == 1) ? acc1 : acc2;
      int n = c * 48 + nt * 16 + colc;
      int gsel = n >> 8, jj = n & 255;
      const float* bp = (gsel == 0) ? bu : (gsel == 1) ? br : bn;
      float bias = bp[jj];
#pragma unroll
      for (int rr = 0; rr < 4; ++rr) {
        int m = rbase + rr;  // batch
        half_t hv = (half_t)(a[rr] + bias);
        if (gsel < 2) {
          ((unsigned short*)hs)[(((size_t)m * TT + t) * HH + jj) * 2 + gsel] =
              __builtin_bit_cast(unsigned short, hv);
        } else {
          nbuf[((size_t)tl * BQ + m) * HH + jj] = hv;
        }
      }
    }
    __syncthreads();
  }
}

// ---------------- Phase B: sequential scan via MFMA ----------------
// One block per batch, 512 threads (8 waves). Wave w owns gate rows
// [32w, 32w+32) of u, r AND n (two 16-col tiles). Matvec = MFMA 16x16x32 with
// h BROADCAST into all 16 A-rows (every lane supplies the same k-slice), so
// all D rows are equal: K-reduction happens inside the matrix unit -- no
// cross-lane reduce at all. Weights (48 tiles x 4 regs = 192 regs) live in
// AGPRs, which MFMA reads natively (the R2-R6 accvgpr_read tax disappears).
// accR (z preactivation) carries from phase 1 to phase 2 in-register; h master
// (hm0, hm1) lives in per-lane registers (all q-groups redundantly).
// Barriers drain lgkm only -> gate prefetch (depth 2) survives.
// rt uses Wu/xu, zt uses Wr/xr (reference naming quirk); n input is (rt*h)@Wn_h^T.
__global__ __launch_bounds__(512, 2) void gru_rec(
    float* __restrict__ hs,           // u/r gate stash + h output
    const half_t* __restrict__ nbuf,  // n-gate chunk
    const float* __restrict__ h0,
    const float* __restrict__ Wu, const float* __restrict__ Wr,
    const float* __restrict__ Wn,
    float* __restrict__ ht, float* __restrict__ hws,
    int t0, int t1)
{
  __shared__ __align__(16) half_t h2buf[256];
  __shared__ __align__(16) half_t rh2buf[256];

  const int b = blockIdx.x;
  const int tid = threadIdx.x;
  const int w = tid >> 6;     // wave 0..7
  const int lane = tid & 63;
  const int c16 = lane & 15;  // column within 16-tile
  const int q = lane >> 4;    // k-slot 0..3
  const int n0 = 32 * w;      // gate-row base for this wave
  const int j0 = n0 + c16;         // tile-0 row
  const int j1 = n0 + 16 + c16;    // tile-1 row

  // B-fragments: w?[ct][kt] = W[n0+ct*16+c16][EE + kt*32 + q*8 .. +8]
  h8_t wu[2][8], wr[2][8], wn[2][8];
#pragma unroll
  for (int ct = 0; ct < 2; ++ct) {
    const int j = n0 + ct * 16 + c16;
    const float* pu = Wu + (size_t)j * (EE + HH) + EE + q * 8;
    const float* pr = Wr + (size_t)j * (EE + HH) + EE + q * 8;
    const float* pn = Wn + (size_t)j * (EE + HH) + EE + q * 8;
#pragma unroll
    for (int kt = 0; kt < 8; ++kt) {
      wu[ct][kt] = cvt_w8(pu + kt * 32);
      wr[ct][kt] = cvt_w8(pr + kt * 32);
      wn[ct][kt] = cvt_w8(pn + kt * 32);
    }
  }

  float hm0, hm1;
  {
    const float* hsrc = (t0 == 0) ? (h0 + (size_t)b * HH) : (hws + (size_t)b * HH);
    hm0 = hsrc[j0];
    hm1 = hsrc[j1];
    if (tid < 256) h2buf[tid] = (half_t)hsrc[tid];
  }
  __syncthreads();

  const uint32* urp = (const uint32*)hs + ((size_t)b * TT + t0) * HH;
  const half_t* np = nbuf + (size_t)b * HH;
  float* hout = hs + ((size_t)b * TT + t0) * HH;

  const int nT = t1 - t0;
  uint32 urA0 = urp[j0], urB0 = urp[j1];
  half_t xnA0 = np[j0], xnB0 = np[j1];
  const size_t s1 = (size_t)((nT > 1) ? 1 : 0);
  uint32 urA1 = urp[s1 * HH + j0], urB1 = urp[s1 * HH + j1];
  half_t xnA1 = np[s1 * BQ * HH + j0], xnB1 = np[s1 * BQ * HH + j1];

  const f32x4 z4 = {0.f, 0.f, 0.f, 0.f};

  for (int tl = 0; tl < nT; ++tl) {
    const size_t t2 = (size_t)((tl + 2 < nT) ? (tl + 2) : (nT - 1));
    uint32 urA2 = urp[t2 * HH + j0], urB2 = urp[t2 * HH + j1];  // in flight
    half_t xnA2 = np[t2 * BQ * HH + j0], xnB2 = np[t2 * BQ * HH + j1];

    // ---- phase 1: u,r matvecs over h (A = broadcast h) ----
    h8_t ha[8];
#pragma unroll
    for (int kt = 0; kt < 8; ++kt) ha[kt] = *(const h8_t*)(h2buf + kt * 32 + q * 8);
    f32x4 aU0 = z4, aU1 = z4, aR0 = z4, aR1 = z4;
#pragma unroll
    for (int kt = 0; kt < 8; ++kt) {
      aU0 = __builtin_amdgcn_mfma_f32_16x16x32_f16(ha[kt], wu[0][kt], aU0, 0, 0, 0);
      aU1 = __builtin_amdgcn_mfma_f32_16x16x32_f16(ha[kt], wu[1][kt], aU1, 0, 0, 0);
      aR0 = __builtin_amdgcn_mfma_f32_16x16x32_f16(ha[kt], wr[0][kt], aR0, 0, 0, 0);
      aR1 = __builtin_amdgcn_mfma_f32_16x16x32_f16(ha[kt], wr[1][kt], aR1, 0, 0, 0);
    }
    float xuA = (float)__builtin_bit_cast(half_t, (unsigned short)(urA0 & 0xffffu));
    float xuB = (float)__builtin_bit_cast(half_t, (unsigned short)(urB0 & 0xffffu));
    float rt0 = sigmoid_f(xuA + aU0[0]);
    float rt1 = sigmoid_f(xuB + aU1[0]);
    if (q == 0) {
      rh2buf[j0] = (half_t)(rt0 * hm0);  // rt * h (pre-matmul!)
      rh2buf[j1] = (half_t)(rt1 * hm1);
    }
    barrier_lgkm();

    // ---- phase 2: n matvec over rt*h, z from carried accR, state update ----
    h8_t ra[8];
#pragma unroll
    for (int kt = 0; kt < 8; ++kt) ra[kt] = *(const h8_t*)(rh2buf + kt * 32 + q * 8);
    f32x4 aN0 = z4, aN1 = z4;
#pragma unroll
    for (int kt = 0; kt < 8; ++kt) {
      aN0 = __builtin_amdgcn_mfma_f32_16x16x32_f16(ra[kt], wn[0][kt], aN0, 0, 0, 0);
      aN1 = __builtin_amdgcn_mfma_f32_16x16x32_f16(ra[kt], wn[1][kt], aN1, 0, 0, 0);
    }
    float xrA = (float)__builtin_bit_cast(half_t, (unsigned short)(urA0 >> 16));
    float xrB = (float)__builtin_bit_cast(half_t, (unsigned short)(urB0 >> 16));
    float zt0 = sigmoid_f(xrA + aR0[0]);
    float zt1 = sigmoid_f(xrB + aR1[0]);
    float p0 = (float)xnA0 + aN0[0];
    float p1 = (float)xnB0 + aN1[0];
    p0 = fminf(fmaxf(p0, -15.f), 15.f);
    p1 = fminf(fmaxf(p1, -15.f), 15.f);
    float e0 = __expf(-2.f * p0), e1 = __expf(-2.f * p1);
    float nv0 = (1.f - e0) * FRCP(1.f + e0);
    float nv1 = (1.f - e1) * FRCP(1.f + e1);
    float hn0 = (1.f - zt0) * nv0 + zt0 * hm0;
    float hn1 = (1.f - zt1) * nv1 + zt1 * hm1;
    hm0 = hn0;
    hm1 = hn1;
    if (q == 0) {
      h2buf[j0] = (half_t)hn0;
      h2buf[j1] = (half_t)hn1;
      hout[(size_t)tl * HH + j0] = hn0;  // overwrites the consumed u/r slot
      hout[(size_t)tl * HH + j1] = hn1;
    }
    barrier_lgkm();

    urA0 = urA1; urA1 = urA2; urB0 = urB1; urB1 = urB2;
    xnA0 = xnA1; xnA1 = xnA2; xnB0 = xnB1; xnB1 = xnB2;
  }

  if (q == 0) {
    float* dst = (t1 == TT) ? (ht + (size_t)b * HH) : (hws + (size_t)b * HH);
    dst[j0] = hm0;
    dst[j1] = hm1;
  }
}

extern "C" void kernel_launch(void* const* d_in, const int* in_sizes, int n_in,
                              void* d_out, int out_size, void* d_ws, size_t ws_size,
                              hipStream_t stream)
{
  (void)in_sizes; (void)n_in; (void)out_size;
  const float* x  = (const float*)d_in[0];
  const float* h0 = (const float*)d_in[1];
  const float* Wu = (const float*)d_in[2];
  const float* bu = (const float*)d_in[3];
  const float* Wr = (const float*)d_in[4];
  const float* br = (const float*)d_in[5];
  const float* Wn = (const float*)d_in[6];
  const float* bn = (const float*)d_in[7];
  float* hs = (float*)d_out;
  float* ht = hs + (size_t)BQ * TT * HH;
  float* hws = (float*)d_ws;                      // 64 KB h carry
  half_t* nbuf = (half_t*)((char*)d_ws + 65536);  // n-gate chunks

  const size_t per_step = (size_t)BQ * HH * sizeof(half_t);  // 32 KB/step
  size_t avail = (ws_size > 65536) ? ws_size - 65536 : 0;
  int Tc = (int)(avail / per_step);
  if (Tc > TT) Tc = TT;
  if (Tc < 1) Tc = 1;

  for (int t0 = 0; t0 < TT; t0 += Tc) {
    int tc = (TT - t0 < Tc) ? (TT - t0) : Tc;
    gru_xproj<<<dim3(tc), 256, 0, stream>>>(x, Wu, bu, Wr, br, Wn, bn, hs, nbuf, t0);
    gru_rec<<<dim3(BQ), 512, 0, stream>>>(hs, nbuf, h0, Wu, Wr, Wn, ht, hws, t0, t0 + tc);
  }
}